// Round 1
// baseline (439.952 us; speedup 1.0000x reference)
//
#include <hip/hip_runtime.h>
#include <math.h>

// Problem constants: B=16384, DMODEL=64, NPTS=1323
#define BATCH   16384
#define DMODEL  64
#define NPTS    1323u
#define TOTAL_PTS (16384u * 1323u)                    // 21,676,032
#define PTS_PER_THREAD 8u
#define STREAM_THREADS (TOTAL_PTS / PTS_PER_THREAD)   // 2,709,504
#define STREAM_BLOCKS  (STREAM_THREADS / 256u)        // 10,584 exactly
#define PARAM_BLOCKS   (BATCH / 4)                    // 4,096 (one wave per row)

// 1.5 * log(2*pi)
#define C_15LOG2PI 2.7568155996140194f

typedef float f4 __attribute__((ext_vector_type(4)));

__device__ __forceinline__ float wave_reduce_sum64(float v) {
#pragma unroll
    for (int off = 32; off > 0; off >>= 1)
        v += __shfl_xor(v, off, 64);
    return v;
}

__device__ __forceinline__ float softplus_f(float x) {
    return log1pf(expf(x));   // x in (0,1): no overflow
}
__device__ __forceinline__ float sigmoid_f(float x) {
    return 1.0f / (1.0f + expf(-x));
}

// ---------------------------------------------------------------------------
// Kernel 1: per-row Cholesky params -> d_ws. One wave per row, 4 rows/block.
// 16384 rows x 3 float4 = 768 KB; stays L2/L3-resident for kernel 2.
// Off the streaming critical path: latency-bound, ~few us.
// layout per row: (m0,m1,m2,iL00) (L10,iL11,L20,L21) (iL22,cc,0,0)
// ---------------------------------------------------------------------------
__global__ __launch_bounds__(256) void mvn_params_kernel(
    const float* __restrict__ rep,    // (B, 64)
    const float* __restrict__ Wm,     // (3, 64)
    const float* __restrict__ bm,     // (3,)
    const float* __restrict__ Ws,     // (6, 64)
    const float* __restrict__ bs,     // (6,)
    f4* __restrict__ P)               // (B, 3) float4
{
    const unsigned tid  = threadIdx.x;
    const unsigned wave = tid >> 6;
    const unsigned lane = tid & 63u;
    const unsigned row  = blockIdx.x * 4u + wave;

    const float r = rep[(size_t)row * DMODEL + lane];

    float d0 = r * Wm[0*64 + lane];
    float d1 = r * Wm[1*64 + lane];
    float d2 = r * Wm[2*64 + lane];
    float s0 = r * Ws[0*64 + lane];
    float s1 = r * Ws[1*64 + lane];
    float s2 = r * Ws[2*64 + lane];
    float s3 = r * Ws[3*64 + lane];
    float s4 = r * Ws[4*64 + lane];
    float s5 = r * Ws[5*64 + lane];

    d0 = wave_reduce_sum64(d0);
    d1 = wave_reduce_sum64(d1);
    d2 = wave_reduce_sum64(d2);
    s0 = wave_reduce_sum64(s0);
    s1 = wave_reduce_sum64(s1);
    s2 = wave_reduce_sum64(s2);
    s3 = wave_reduce_sum64(s3);
    s4 = wave_reduce_sum64(s4);
    s5 = wave_reduce_sum64(s5);

    if (lane == 0) {
        const float m0 = d0 + bm[0];
        const float m1 = d1 + bm[1];
        const float m2 = d2 + bm[2];

        const float L00 = softplus_f(sigmoid_f(s0 + bs[0]));
        const float L10 = sigmoid_f(s1 + bs[1]);
        const float L11 = softplus_f(sigmoid_f(s2 + bs[2]));
        const float L20 = sigmoid_f(s3 + bs[3]);
        const float L21 = sigmoid_f(s4 + bs[4]);
        const float L22 = softplus_f(sigmoid_f(s5 + bs[5]));

        const float cc = -(logf(L00) + logf(L11) + logf(L22)) - C_15LOG2PI;

        f4 q0; q0.x = m0;         q0.y = m1;  q0.z = m2;  q0.w = 1.0f / L00;
        f4 q1; q1.x = L10;        q1.y = 1.0f / L11; q1.z = L20; q1.w = L21;
        f4 q2; q2.x = 1.0f / L22; q2.y = cc;  q2.z = 0.0f; q2.w = 0.0f;
        f4* Pr = P + (size_t)row * 3u;
        Pr[0] = q0; Pr[1] = q1; Pr[2] = q2;
    }
}

__device__ __forceinline__ float eval_pt(float x, float y, float z,
                                         const f4 q0, const f4 q1, const f4 q2)
{
    const float e0 = x - q0.x;
    const float e1 = y - q0.y;
    const float e2 = z - q0.z;
    const float z0 = e0 * q0.w;
    const float z1 = fmaf(-q1.x, z0, e1) * q1.y;
    const float z2 = fmaf(-q1.w, z1, fmaf(-q1.z, z0, e2)) * q2.x;
    const float maha = fmaf(z0, z0, fmaf(z1, z1, z2 * z2));
    return __expf(fmaf(-0.5f, maha, q2.y));
}

// ---------------------------------------------------------------------------
// Kernel 2: pure streaming. 8 points/thread (6 float4 nt-loads in flight,
// 2 float4 nt-stores). No LDS, no barrier, no reductions -> max occupancy,
// max MLP. Param reads are cached (L1/L2 broadcast; nt streams don't evict).
// ---------------------------------------------------------------------------
__global__ __launch_bounds__(256) void mvn_stream_kernel(
    const float* __restrict__ dxyz,   // (B, NPTS, 3)
    const f4* __restrict__ P,         // (B, 3) params
    float* __restrict__ out)          // (B, NPTS)
{
    const unsigned gid = blockIdx.x * 256u + threadIdx.x;

    // issue all stream loads first
    const f4* __restrict__ src = (const f4*)dxyz + (size_t)gid * 6u;
    const f4 a = __builtin_nontemporal_load(src + 0);
    const f4 b = __builtin_nontemporal_load(src + 1);
    const f4 c = __builtin_nontemporal_load(src + 2);
    const f4 d = __builtin_nontemporal_load(src + 3);
    const f4 e = __builtin_nontemporal_load(src + 4);
    const f4 f = __builtin_nontemporal_load(src + 5);

    const unsigned p0  = gid * 8u;
    const unsigned row = p0 / NPTS;            // magic-mul
    const unsigned rem = p0 - row * NPTS;

    const f4* Pq = P + (size_t)row * 3u;
    const f4 q0 = Pq[0], q1 = Pq[1], q2 = Pq[2];

    f4 o0, o1;
    if (rem <= NPTS - 8u) {
        // all 8 points in this row (99.5% of threads)
        o0.x = eval_pt(a.x, a.y, a.z, q0, q1, q2);
        o0.y = eval_pt(a.w, b.x, b.y, q0, q1, q2);
        o0.z = eval_pt(b.z, b.w, c.x, q0, q1, q2);
        o0.w = eval_pt(c.y, c.z, c.w, q0, q1, q2);
        o1.x = eval_pt(d.x, d.y, d.z, q0, q1, q2);
        o1.y = eval_pt(d.w, e.x, e.y, q0, q1, q2);
        o1.z = eval_pt(e.z, e.w, f.x, q0, q1, q2);
        o1.w = eval_pt(f.y, f.z, f.w, q0, q1, q2);
    } else {
        // spans a row boundary; row+1 < BATCH guaranteed (last row's
        // tail thread always satisfies rem <= NPTS-8)
        const f4 r0 = Pq[3], r1 = Pq[4], r2 = Pq[5];
#define SEL(i, X, Y, Z, DST)                                              \
        {                                                                 \
            const bool in0 = (rem + (i)) < NPTS;                          \
            const f4 u0 = in0 ? q0 : r0;                                  \
            const f4 u1 = in0 ? q1 : r1;                                  \
            const f4 u2 = in0 ? q2 : r2;                                  \
            DST = eval_pt(X, Y, Z, u0, u1, u2);                           \
        }
        SEL(0u, a.x, a.y, a.z, o0.x)
        SEL(1u, a.w, b.x, b.y, o0.y)
        SEL(2u, b.z, b.w, c.x, o0.z)
        SEL(3u, c.y, c.z, c.w, o0.w)
        SEL(4u, d.x, d.y, d.z, o1.x)
        SEL(5u, d.w, e.x, e.y, o1.y)
        SEL(6u, e.z, e.w, f.x, o1.z)
        SEL(7u, f.y, f.z, f.w, o1.w)
#undef SEL
    }

    f4* dst = (f4*)out + (size_t)gid * 2u;
    __builtin_nontemporal_store(o0, dst + 0);
    __builtin_nontemporal_store(o1, dst + 1);
}

extern "C" void kernel_launch(void* const* d_in, const int* in_sizes, int n_in,
                              void* d_out, int out_size, void* d_ws, size_t ws_size,
                              hipStream_t stream) {
    const float* rep  = (const float*)d_in[0];
    const float* dxyz = (const float*)d_in[1];
    const float* Wm   = (const float*)d_in[2];
    const float* bm   = (const float*)d_in[3];
    const float* Ws   = (const float*)d_in[4];
    const float* bs   = (const float*)d_in[5];
    float* out = (float*)d_out;
    f4* P = (f4*)d_ws;   // 16384 * 3 * 16 B = 768 KB

    mvn_params_kernel<<<PARAM_BLOCKS, 256, 0, stream>>>(rep, Wm, bm, Ws, bs, P);
    mvn_stream_kernel<<<STREAM_BLOCKS, 256, 0, stream>>>(dxyz, P, out);
}

// Round 2
// 401.165 us; speedup vs baseline: 1.0967x; 1.0967x over previous
//
#include <hip/hip_runtime.h>
#include <math.h>

// Problem constants: B=16384, DMODEL=64, NPTS=1323
#define BATCH   16384
#define DMODEL  64
#define NPTS    1323u
#define TOTAL_PTS (16384u * 1323u)                    // 21,676,032 (divisible by 4)
#define PTS_PER_THREAD 4u
#define STREAM_THREADS (TOTAL_PTS / PTS_PER_THREAD)   // 5,419,008
#define STREAM_BLOCKS  (STREAM_THREADS / 256u)        // 21,168 exactly
#define PARAM_BLOCKS   (BATCH / 4)                    // 4,096 (one wave per row)

// 1.5 * log(2*pi)
#define C_15LOG2PI 2.7568155996140194f

typedef float f4 __attribute__((ext_vector_type(4)));

__device__ __forceinline__ float wave_reduce_sum64(float v) {
#pragma unroll
    for (int off = 32; off > 0; off >>= 1)
        v += __shfl_xor(v, off, 64);
    return v;
}

__device__ __forceinline__ float softplus_f(float x) {
    return log1pf(expf(x));   // x in (0,1): no overflow
}
__device__ __forceinline__ float sigmoid_f(float x) {
    return 1.0f / (1.0f + expf(-x));
}

// ---------------------------------------------------------------------------
// Kernel 1: per-row Cholesky params -> d_ws. One wave per row, 4 rows/block.
// 16384 rows x 3 float4 = 768 KB; stays L2/L3-resident for kernel 2.
// layout per row: (m0,m1,m2,iL00) (L10,iL11,L20,L21) (iL22,cc,0,0)
// ---------------------------------------------------------------------------
__global__ __launch_bounds__(256) void mvn_params_kernel(
    const float* __restrict__ rep,    // (B, 64)
    const float* __restrict__ Wm,     // (3, 64)
    const float* __restrict__ bm,     // (3,)
    const float* __restrict__ Ws,     // (6, 64)
    const float* __restrict__ bs,     // (6,)
    f4* __restrict__ P)               // (B, 3) float4
{
    const unsigned tid  = threadIdx.x;
    const unsigned wave = tid >> 6;
    const unsigned lane = tid & 63u;
    const unsigned row  = blockIdx.x * 4u + wave;

    const float r = rep[(size_t)row * DMODEL + lane];

    float d0 = r * Wm[0*64 + lane];
    float d1 = r * Wm[1*64 + lane];
    float d2 = r * Wm[2*64 + lane];
    float s0 = r * Ws[0*64 + lane];
    float s1 = r * Ws[1*64 + lane];
    float s2 = r * Ws[2*64 + lane];
    float s3 = r * Ws[3*64 + lane];
    float s4 = r * Ws[4*64 + lane];
    float s5 = r * Ws[5*64 + lane];

    d0 = wave_reduce_sum64(d0);
    d1 = wave_reduce_sum64(d1);
    d2 = wave_reduce_sum64(d2);
    s0 = wave_reduce_sum64(s0);
    s1 = wave_reduce_sum64(s1);
    s2 = wave_reduce_sum64(s2);
    s3 = wave_reduce_sum64(s3);
    s4 = wave_reduce_sum64(s4);
    s5 = wave_reduce_sum64(s5);

    if (lane == 0) {
        const float m0 = d0 + bm[0];
        const float m1 = d1 + bm[1];
        const float m2 = d2 + bm[2];

        const float L00 = softplus_f(sigmoid_f(s0 + bs[0]));
        const float L10 = sigmoid_f(s1 + bs[1]);
        const float L11 = softplus_f(sigmoid_f(s2 + bs[2]));
        const float L20 = sigmoid_f(s3 + bs[3]);
        const float L21 = sigmoid_f(s4 + bs[4]);
        const float L22 = softplus_f(sigmoid_f(s5 + bs[5]));

        const float cc = -(logf(L00) + logf(L11) + logf(L22)) - C_15LOG2PI;

        f4 q0; q0.x = m0;         q0.y = m1;         q0.z = m2;   q0.w = 1.0f / L00;
        f4 q1; q1.x = L10;        q1.y = 1.0f / L11; q1.z = L20;  q1.w = L21;
        f4 q2; q2.x = 1.0f / L22; q2.y = cc;         q2.z = 0.0f; q2.w = 0.0f;
        f4* Pr = P + (size_t)row * 3u;
        Pr[0] = q0; Pr[1] = q1; Pr[2] = q2;
    }
}

__device__ __forceinline__ float eval_pt(float x, float y, float z,
                                         const f4 q0, const f4 q1, const f4 q2)
{
    const float e0 = x - q0.x;
    const float e1 = y - q0.y;
    const float e2 = z - q0.z;
    const float z0 = e0 * q0.w;
    const float z1 = fmaf(-q1.x, z0, e1) * q1.y;
    const float z2 = fmaf(-q1.w, z1, fmaf(-q1.z, z0, e2)) * q2.x;
    const float maha = fmaf(z0, z0, fmaf(z1, z1, z2 * z2));
    return __expf(fmaf(-0.5f, maha, q2.y));
}

// ---------------------------------------------------------------------------
// Kernel 2: pure streaming. 4 points/thread: 3 float4 loads (lane stride
// 48 B, the round-0-proven pattern), 1 fully-coalesced float4 store.
// No LDS, no barrier, no reductions. Params come from the L2-resident P.
// ---------------------------------------------------------------------------
__global__ __launch_bounds__(256) void mvn_stream_kernel(
    const float* __restrict__ dxyz,   // (B, NPTS, 3)
    const f4* __restrict__ P,         // (B, 3) params
    float* __restrict__ out)          // (B, NPTS)
{
    const unsigned gid = blockIdx.x * 256u + threadIdx.x;

    // issue streaming loads first (longest latency)
    const f4* __restrict__ src = (const f4*)dxyz + (size_t)gid * 3u;
    const f4 a = src[0];
    const f4 b = src[1];
    const f4 c = src[2];

    const unsigned p0  = gid * 4u;
    const unsigned row = p0 / NPTS;            // magic-mul
    const unsigned rem = p0 - row * NPTS;

    // params: 48 B per row, L2-hit (768 KB buffer), mostly wave-uniform
    const f4* Pq = P + (size_t)row * 3u;
    const f4 q0 = Pq[0], q1 = Pq[1], q2 = Pq[2];

    f4 o;
    if (rem <= NPTS - 4u) {
        // all 4 points in this row (common case; also covers the very
        // last thread: rem == NPTS-4 exactly)
        o.x = eval_pt(a.x, a.y, a.z, q0, q1, q2);
        o.y = eval_pt(a.w, b.x, b.y, q0, q1, q2);
        o.z = eval_pt(b.z, b.w, c.x, q0, q1, q2);
        o.w = eval_pt(c.y, c.z, c.w, q0, q1, q2);
    } else {
        // spans a row boundary (row+1 is valid: last row's tail thread
        // always hits the common case above)
        const f4 r0 = Pq[3], r1 = Pq[4], r2 = Pq[5];
        const f4 u0 = (rem + 0u < NPTS) ? q0 : r0;
        const f4 u1 = (rem + 0u < NPTS) ? q1 : r1;
        const f4 u2 = (rem + 0u < NPTS) ? q2 : r2;
        o.x = eval_pt(a.x, a.y, a.z, u0, u1, u2);
        const f4 v0 = (rem + 1u < NPTS) ? q0 : r0;
        const f4 v1 = (rem + 1u < NPTS) ? q1 : r1;
        const f4 v2 = (rem + 1u < NPTS) ? q2 : r2;
        o.y = eval_pt(a.w, b.x, b.y, v0, v1, v2);
        const f4 w0 = (rem + 2u < NPTS) ? q0 : r0;
        const f4 w1 = (rem + 2u < NPTS) ? q1 : r1;
        const f4 w2 = (rem + 2u < NPTS) ? q2 : r2;
        o.z = eval_pt(b.z, b.w, c.x, w0, w1, w2);
        o.w = eval_pt(c.y, c.z, c.w, r0, r1, r2);  // rem+3 >= NPTS here
    }

    ((f4*)out)[gid] = o;
}

extern "C" void kernel_launch(void* const* d_in, const int* in_sizes, int n_in,
                              void* d_out, int out_size, void* d_ws, size_t ws_size,
                              hipStream_t stream) {
    const float* rep  = (const float*)d_in[0];
    const float* dxyz = (const float*)d_in[1];
    const float* Wm   = (const float*)d_in[2];
    const float* bm   = (const float*)d_in[3];
    const float* Ws   = (const float*)d_in[4];
    const float* bs   = (const float*)d_in[5];
    float* out = (float*)d_out;
    f4* P = (f4*)d_ws;   // 16384 * 3 * 16 B = 768 KB

    mvn_params_kernel<<<PARAM_BLOCKS, 256, 0, stream>>>(rep, Wm, bm, Ws, bs, P);
    mvn_stream_kernel<<<STREAM_BLOCKS, 256, 0, stream>>>(dxyz, P, out);
}

// Round 3
// 394.241 us; speedup vs baseline: 1.1159x; 1.0176x over previous
//
#include <hip/hip_runtime.h>
#include <math.h>

// Problem constants: B=16384, DMODEL=64, NPTS=1323
#define BATCH   16384
#define DMODEL  64
#define NPTS    1323u

// Exact decomposition: TOTAL_PTS = 16384*1323 = 21,676,032 = 2048 * 10584,
// and 10584 = 8 * 1323  ->  each block owns exactly 8 rows.
#define ROWS_PER_BLOCK 8u
#define PTS_PER_BLOCK  (ROWS_PER_BLOCK * NPTS)        // 10584
#define NBLOCKS        (BATCH / ROWS_PER_BLOCK)       // 2048 (8 blocks/CU)
#define FULL_ITERS     10u                            // 10 * 1024 = 10240 pts
#define TAIL_THREADS   ((PTS_PER_BLOCK - FULL_ITERS * 1024u) / 4u)  // 86

// 1.5 * log(2*pi)
#define C_15LOG2PI 2.7568155996140194f

typedef float f4 __attribute__((ext_vector_type(4)));

__device__ __forceinline__ float wave_reduce_sum64(float v) {
#pragma unroll
    for (int off = 32; off > 0; off >>= 1)
        v += __shfl_xor(v, off, 64);
    return v;
}

__device__ __forceinline__ float softplus_f(float x) {
    return log1pf(expf(x));   // x in (0,1): no overflow
}
__device__ __forceinline__ float sigmoid_f(float x) {
    return 1.0f / (1.0f + expf(-x));
}

__device__ __forceinline__ float eval_pt(float x, float y, float z,
                                         const f4 q0, const f4 q1, const f4 q2)
{
    const float e0 = x - q0.x;
    const float e1 = y - q0.y;
    const float e2 = z - q0.z;
    const float z0 = e0 * q0.w;
    const float z1 = fmaf(-q1.x, z0, e1) * q1.y;
    const float z2 = fmaf(-q1.w, z1, fmaf(-q1.z, z0, e2)) * q2.x;
    const float maha = fmaf(z0, z0, fmaf(z1, z1, z2 * z2));
    return __expf(fmaf(-0.5f, maha, q2.y));
}

// ---------------------------------------------------------------------------
// Single persistent-style kernel. 2048 blocks x 256 threads (G11: memory-
// bound -> ~2048 blocks). Block b owns rows [8b, 8b+8) == points
// [b*10584, (b+1)*10584). Prologue computes the 8 rows' params ONCE into
// 384 B of LDS (amortized over ~60 us block lifetime vs. every 1024 pts in
// the round-0 fused version). Main loop = round-0-proven memory pattern:
// 3 coalesced float4 loads + 1 coalesced float4 store, no nontemporal.
// ---------------------------------------------------------------------------
__global__ __launch_bounds__(256) void mvn_fused8_kernel(
    const float* __restrict__ rep,    // (B, 64)
    const float* __restrict__ dxyz,   // (B, NPTS, 3)
    const float* __restrict__ Wm,     // (3, 64)
    const float* __restrict__ bm,     // (3,)
    const float* __restrict__ Ws,     // (6, 64)
    const float* __restrict__ bs,     // (6,)
    float* __restrict__ out)          // (B, NPTS)
{
    // per row: [0..2]=m, [3]=1/L00, [4]=L10, [5]=1/L11, [6]=L20, [7]=L21,
    //          [8]=1/L22, [9]=cc, [10..11]=pad. Row stride 48 B.
    __shared__ float P[ROWS_PER_BLOCK][12];

    const unsigned tid  = threadIdx.x;
    const unsigned wave = tid >> 6;
    const unsigned lane = tid & 63u;
    const unsigned rowBase = blockIdx.x * ROWS_PER_BLOCK;

    // ---- prologue: raw GEMV sums for 8 rows (wave w -> rows 2w, 2w+1) ----
    {
        const unsigned rA = rowBase + 2u * wave;
        const float xA = rep[(size_t)rA * DMODEL + lane];
        const float xB = rep[(size_t)(rA + 1u) * DMODEL + lane];
        float wv[9];
#pragma unroll
        for (int j = 0; j < 3; ++j) wv[j] = Wm[j * 64 + lane];
#pragma unroll
        for (int j = 0; j < 6; ++j) wv[3 + j] = Ws[j * 64 + lane];
#pragma unroll
        for (int j = 0; j < 9; ++j) {
            const float sa = wave_reduce_sum64(xA * wv[j]);
            const float sb = wave_reduce_sum64(xB * wv[j]);
            if (lane == 0) {
                P[2u * wave][j]      = sa;
                P[2u * wave + 1u][j] = sb;
            }
        }
    }
    __syncthreads();

    // ---- 8 threads finish the transcendental chains in parallel ----
    if (tid < ROWS_PER_BLOCK) {
        const float d0 = P[tid][0], d1 = P[tid][1], d2 = P[tid][2];
        const float s0 = P[tid][3], s1 = P[tid][4], s2 = P[tid][5];
        const float s3 = P[tid][6], s4 = P[tid][7], s5 = P[tid][8];

        const float m0 = d0 + bm[0];
        const float m1 = d1 + bm[1];
        const float m2 = d2 + bm[2];

        const float L00 = softplus_f(sigmoid_f(s0 + bs[0]));
        const float L10 = sigmoid_f(s1 + bs[1]);
        const float L11 = softplus_f(sigmoid_f(s2 + bs[2]));
        const float L20 = sigmoid_f(s3 + bs[3]);
        const float L21 = sigmoid_f(s4 + bs[4]);
        const float L22 = softplus_f(sigmoid_f(s5 + bs[5]));

        const float cc = -(logf(L00) + logf(L11) + logf(L22)) - C_15LOG2PI;

        P[tid][0] = m0;          P[tid][1] = m1;  P[tid][2] = m2;
        P[tid][3] = 1.0f / L00;  P[tid][4] = L10; P[tid][5] = 1.0f / L11;
        P[tid][6] = L20;         P[tid][7] = L21; P[tid][8] = 1.0f / L22;
        P[tid][9] = cc;          P[tid][10] = 0.0f; P[tid][11] = 0.0f;
    }
    __syncthreads();

    // ---- main streaming loop over the block's 10584 points ----
    const f4* __restrict__ src = (const f4*)dxyz;
    f4* __restrict__ dst = (f4*)out;
    const unsigned qBase = blockIdx.x * (PTS_PER_BLOCK / 4u);  // *2646

#define BODY(LP, GQ)                                                        \
    {                                                                       \
        const unsigned lp  = (LP);                                          \
        const unsigned gq  = (GQ);                                          \
        const f4 a = src[(size_t)gq * 3u + 0u];                             \
        const f4 b = src[(size_t)gq * 3u + 1u];                             \
        const f4 c = src[(size_t)gq * 3u + 2u];                             \
        /* lp < 10584 < 2^14: exact /1323 via 24-bit magic */               \
        const unsigned rowL = (lp * 12682u) >> 24;                          \
        const unsigned rem  = lp - rowL * NPTS;                             \
        const f4* Pq = (const f4*)P[rowL];                                  \
        const f4 q0 = Pq[0], q1 = Pq[1], q2 = Pq[2];                        \
        f4 o;                                                               \
        if (rem <= NPTS - 4u) {                                             \
            o.x = eval_pt(a.x, a.y, a.z, q0, q1, q2);                       \
            o.y = eval_pt(a.w, b.x, b.y, q0, q1, q2);                       \
            o.z = eval_pt(b.z, b.w, c.x, q0, q1, q2);                       \
            o.w = eval_pt(c.y, c.z, c.w, q0, q1, q2);                       \
        } else {                                                            \
            /* crossing rows are always <7 within a block (alignment) */    \
            const f4 r0 = Pq[3], r1 = Pq[4], r2 = Pq[5];                    \
            const f4 u0 = (rem + 0u < NPTS) ? q0 : r0;                      \
            const f4 u1 = (rem + 0u < NPTS) ? q1 : r1;                      \
            const f4 u2 = (rem + 0u < NPTS) ? q2 : r2;                      \
            o.x = eval_pt(a.x, a.y, a.z, u0, u1, u2);                       \
            const f4 v0 = (rem + 1u < NPTS) ? q0 : r0;                      \
            const f4 v1 = (rem + 1u < NPTS) ? q1 : r1;                      \
            const f4 v2 = (rem + 1u < NPTS) ? q2 : r2;                      \
            o.y = eval_pt(a.w, b.x, b.y, v0, v1, v2);                       \
            const f4 w0 = (rem + 2u < NPTS) ? q0 : r0;                      \
            const f4 w1 = (rem + 2u < NPTS) ? q1 : r1;                      \
            const f4 w2 = (rem + 2u < NPTS) ? q2 : r2;                      \
            o.z = eval_pt(b.z, b.w, c.x, w0, w1, w2);                       \
            o.w = eval_pt(c.y, c.z, c.w, r0, r1, r2); /* rem+3 >= NPTS */   \
        }                                                                   \
        dst[gq] = o;                                                        \
    }

#pragma unroll 2
    for (unsigned it = 0; it < FULL_ITERS; ++it) {
        BODY(it * 1024u + tid * 4u, qBase + it * 256u + tid);
    }
    // tail: 344 points = 86 threads; provably all inside row 7 (no crossing)
    if (tid < TAIL_THREADS) {
        BODY(FULL_ITERS * 1024u + tid * 4u, qBase + FULL_ITERS * 256u + tid);
    }
#undef BODY
}

extern "C" void kernel_launch(void* const* d_in, const int* in_sizes, int n_in,
                              void* d_out, int out_size, void* d_ws, size_t ws_size,
                              hipStream_t stream) {
    const float* rep  = (const float*)d_in[0];
    const float* dxyz = (const float*)d_in[1];
    const float* Wm   = (const float*)d_in[2];
    const float* bm   = (const float*)d_in[3];
    const float* Ws   = (const float*)d_in[4];
    const float* bs   = (const float*)d_in[5];
    float* out = (float*)d_out;

    mvn_fused8_kernel<<<NBLOCKS, 256, 0, stream>>>(rep, dxyz, Wm, bm, Ws, bs, out);
}

// Round 4
// 386.445 us; speedup vs baseline: 1.1385x; 1.0202x over previous
//
#include <hip/hip_runtime.h>
#include <math.h>

// Problem constants: B=16384, DMODEL=64, NPTS=1323
#define BATCH   16384
#define DMODEL  64
#define NPTS    1323u
#define TOTAL_PTS (16384u * 1323u)            // 21,676,032
#define NBLOCKS   (TOTAL_PTS / 1024u)         // 21,168 blocks x 1024 pts

// 1.5 * log(2*pi)
#define C_15LOG2PI 2.7568155996140194f

typedef float f4 __attribute__((ext_vector_type(4)));

__device__ __forceinline__ float wave_reduce_sum64(float v) {
#pragma unroll
    for (int off = 32; off > 0; off >>= 1)
        v += __shfl_xor(v, off, 64);
    return v;
}

__device__ __forceinline__ float softplus_f(float x) {
    return log1pf(expf(x));   // x in (0,1): no overflow
}
__device__ __forceinline__ float sigmoid_f(float x) {
    return 1.0f / (1.0f + expf(-x));
}

__device__ __forceinline__ float eval_pt(float x, float y, float z,
                                         const f4 q0, const f4 q1, const f4 q2)
{
    const float e0 = x - q0.x;
    const float e1 = y - q0.y;
    const float e2 = z - q0.z;
    const float z0 = e0 * q0.w;
    const float z1 = fmaf(-q1.x, z0, e1) * q1.y;
    const float z2 = fmaf(-q1.w, z1, fmaf(-q1.z, z0, e2)) * q2.x;
    const float maha = fmaf(z0, z0, fmaf(z1, z1, z2 * z2));
    return __expf(fmaf(-0.5f, maha, q2.y));
}

// ---------------------------------------------------------------------------
// R0 structure (proven best: 21168 blocks x 1024 pts, in-block param phase)
// with ONE change: contiguous 12B/lane dwordx3 loads instead of 48B-strided
// dwordx4. Thread (wave,lane) handles points blockPt + wave*256 + k*64 + lane
// (k=0..3): every load instruction covers a dense 768B segment. Outputs are
// transposed through 4KB of wave-private LDS back to one coalesced dwordx4
// store per thread.
// ---------------------------------------------------------------------------
__global__ __launch_bounds__(256) void mvn_fused_c3_kernel(
    const float* __restrict__ rep,    // (B, 64)
    const float* __restrict__ dxyz,   // (B, NPTS, 3)
    const float* __restrict__ Wm,     // (3, 64)
    const float* __restrict__ bm,     // (3,)
    const float* __restrict__ Ws,     // (6, 64)
    const float* __restrict__ bs,     // (6,)
    float* __restrict__ out)          // (B, NPTS)
{
    // params for rows r0, r0+1: (m0,m1,m2,iL00)(L10,iL11,L20,L21)(iL22,cc,0,0)
    __shared__ __attribute__((aligned(16))) float P[2][12];
    // output transpose scratch, one 1KB region per wave (wave-private use)
    __shared__ __attribute__((aligned(16))) float X[4][256];

    const unsigned tid  = threadIdx.x;
    const unsigned wave = tid >> 6;
    const unsigned lane = tid & 63u;
    const unsigned blockPt = blockIdx.x * 1024u;

    // ---- issue the 4 contiguous dwordx3 streaming loads first ----
    const unsigned pbase = blockPt + wave * 256u + lane;
    const float* sp = dxyz + (size_t)pbase * 3u;
    const float x0a = sp[0],   x0b = sp[1],   x0c = sp[2];     // k=0
    const float x1a = sp[192], x1b = sp[193], x1c = sp[194];   // k=1 (+64 pts)
    const float x2a = sp[384], x2b = sp[385], x2c = sp[386];   // k=2
    const float x3a = sp[576], x3b = sp[577], x3c = sp[578];   // k=3

    const unsigned r0 = blockPt / NPTS;            // compiler magic-div
    const unsigned boundary = (r0 + 1u) * NPTS;    // first point of row r0+1

    // ---- param phase (R0-proven): waves 0/1 compute rows r0 / r0+1 ----
    if (wave < 2) {
        const unsigned prow = (wave == 0u) ? r0 : min(r0 + 1u, (unsigned)(BATCH - 1));
        const float r = rep[(size_t)prow * DMODEL + lane];

        float d0 = r * Wm[0*64 + lane];
        float d1 = r * Wm[1*64 + lane];
        float d2 = r * Wm[2*64 + lane];
        float s0 = r * Ws[0*64 + lane];
        float s1 = r * Ws[1*64 + lane];
        float s2 = r * Ws[2*64 + lane];
        float s3 = r * Ws[3*64 + lane];
        float s4 = r * Ws[4*64 + lane];
        float s5 = r * Ws[5*64 + lane];

        d0 = wave_reduce_sum64(d0);
        d1 = wave_reduce_sum64(d1);
        d2 = wave_reduce_sum64(d2);
        s0 = wave_reduce_sum64(s0);
        s1 = wave_reduce_sum64(s1);
        s2 = wave_reduce_sum64(s2);
        s3 = wave_reduce_sum64(s3);
        s4 = wave_reduce_sum64(s4);
        s5 = wave_reduce_sum64(s5);

        if (lane == 0) {
            const float m0 = d0 + bm[0];
            const float m1 = d1 + bm[1];
            const float m2 = d2 + bm[2];

            const float L00 = softplus_f(sigmoid_f(s0 + bs[0]));
            const float L10 = sigmoid_f(s1 + bs[1]);
            const float L11 = softplus_f(sigmoid_f(s2 + bs[2]));
            const float L20 = sigmoid_f(s3 + bs[3]);
            const float L21 = sigmoid_f(s4 + bs[4]);
            const float L22 = softplus_f(sigmoid_f(s5 + bs[5]));

            const float cc = -(logf(L00) + logf(L11) + logf(L22)) - C_15LOG2PI;

            float* Pw = P[wave];
            Pw[0] = m0;         Pw[1] = m1;   Pw[2] = m2;   Pw[3] = 1.0f / L00;
            Pw[4] = L10;        Pw[5] = 1.0f / L11;
            Pw[6] = L20;        Pw[7] = L21;
            Pw[8] = 1.0f / L22; Pw[9] = cc;   Pw[10] = 0.0f; Pw[11] = 0.0f;
        }
    }
    __syncthreads();

    // both rows' params into registers (broadcast LDS reads)
    const f4* Pa = (const f4*)P[0];
    const f4 A0 = Pa[0], A1 = Pa[1], A2 = Pa[2];
    const f4* Pb = (const f4*)P[1];
    const f4 B0 = Pb[0], B1 = Pb[1], B2 = Pb[2];

    // ---- evaluate 4 points; row selection = one compare per point ----
    float r0v, r1v, r2v, r3v;
    if (pbase + 192u < boundary) {
        // all 4 points in row r0 (vast majority of threads)
        r0v = eval_pt(x0a, x0b, x0c, A0, A1, A2);
        r1v = eval_pt(x1a, x1b, x1c, A0, A1, A2);
        r2v = eval_pt(x2a, x2b, x2c, A0, A1, A2);
        r3v = eval_pt(x3a, x3b, x3c, A0, A1, A2);
    } else if (pbase >= boundary) {
        // all 4 points in row r0+1
        r0v = eval_pt(x0a, x0b, x0c, B0, B1, B2);
        r1v = eval_pt(x1a, x1b, x1c, B0, B1, B2);
        r2v = eval_pt(x2a, x2b, x2c, B0, B1, B2);
        r3v = eval_pt(x3a, x3b, x3c, B0, B1, B2);
    } else {
        // straddling thread: per-point select
#define EVP(K, XA, XB, XC, DST)                                           \
        {                                                                 \
            const bool in0 = (pbase + (K) * 64u) < boundary;              \
            const f4 q0 = in0 ? A0 : B0;                                  \
            const f4 q1 = in0 ? A1 : B1;                                  \
            const f4 q2 = in0 ? A2 : B2;                                  \
            DST = eval_pt(XA, XB, XC, q0, q1, q2);                        \
        }
        EVP(0u, x0a, x0b, x0c, r0v)
        EVP(1u, x1a, x1b, x1c, r1v)
        EVP(2u, x2a, x2b, x2c, r2v)
        EVP(3u, x3a, x3b, x3c, r3v)
#undef EVP
    }

    // ---- wave-private LDS transpose -> one coalesced dwordx4 store ----
    float* Xw = X[wave];
    Xw[lane]        = r0v;    // lane-stride 4B: conflict-free
    Xw[lane + 64u]  = r1v;
    Xw[lane + 128u] = r2v;
    Xw[lane + 192u] = r3v;
    // same-wave RAW on LDS: hardware-ordered via lgkmcnt (compiler inserts)
    const f4 o = ((const f4*)Xw)[lane];   // contiguous b128, conflict-free
    ((f4*)out)[blockIdx.x * 256u + wave * 64u + lane] = o;
}

extern "C" void kernel_launch(void* const* d_in, const int* in_sizes, int n_in,
                              void* d_out, int out_size, void* d_ws, size_t ws_size,
                              hipStream_t stream) {
    const float* rep  = (const float*)d_in[0];
    const float* dxyz = (const float*)d_in[1];
    const float* Wm   = (const float*)d_in[2];
    const float* bm   = (const float*)d_in[3];
    const float* Ws   = (const float*)d_in[4];
    const float* bs   = (const float*)d_in[5];
    float* out = (float*)d_out;

    mvn_fused_c3_kernel<<<NBLOCKS, 256, 0, stream>>>(rep, dxyz, Wm, bm, Ws, bs, out);
}